// Round 1
// baseline (99.811 us; speedup 1.0000x reference)
//
#include <hip/hip_runtime.h>
#include <hip/hip_bf16.h>

#define B_ 256
#define R_ 36
#define T_ 64
#define D_ 1024

__device__ __forceinline__ float lrelu(float x) { return x >= 0.0f ? x : 0.1f * x; }

// block-wide sum over 256 threads (4 waves)
__device__ __forceinline__ float block_sum(float v, float* sred) {
#pragma unroll
  for (int off = 32; off > 0; off >>= 1) v += __shfl_down(v, off, 64);
  int w = threadIdx.x >> 6;
  if ((threadIdx.x & 63) == 0) sred[w] = v;
  __syncthreads();
  float r = sred[0] + sred[1] + sred[2] + sred[3];
  __syncthreads();
  return r;
}

// ---- cap path: leaky-relu + l2norm over T + masked mean + row-norm ----
__global__ __launch_bounds__(256) void cap_kernel(const float* __restrict__ cap,
    const int* __restrict__ lens, float* __restrict__ cap_mean, float* __restrict__ cap_rn) {
  __shared__ float sred[4];
  int b = blockIdx.x, t = threadIdx.x;
  int len = lens[b];
  const float4* src = reinterpret_cast<const float4*>(cap) + (size_t)b * (T_ * D_ / 4);
  float s2[4] = {0, 0, 0, 0}, sm[4] = {0, 0, 0, 0};
  for (int tt = 0; tt < T_; ++tt) {
    float4 v = src[tt * (D_ / 4) + t];
    float y0 = lrelu(v.x), y1 = lrelu(v.y), y2 = lrelu(v.z), y3 = lrelu(v.w);
    s2[0] += y0 * y0; s2[1] += y1 * y1; s2[2] += y2 * y2; s2[3] += y3 * y3;
    if (tt < len) { sm[0] += y0; sm[1] += y1; sm[2] += y2; sm[3] += y3; }
  }
  float inv_len = 1.0f / (float)len;
  float4 cm;
  cm.x = sm[0] / (sqrtf(s2[0]) + 1e-8f) * inv_len;
  cm.y = sm[1] / (sqrtf(s2[1]) + 1e-8f) * inv_len;
  cm.z = sm[2] / (sqrtf(s2[2]) + 1e-8f) * inv_len;
  cm.w = sm[3] / (sqrtf(s2[3]) + 1e-8f) * inv_len;
  reinterpret_cast<float4*>(cap_mean)[b * (D_ / 4) + t] = cm;
  float sq = cm.x * cm.x + cm.y * cm.y + cm.z * cm.z + cm.w * cm.w;
  float tot = block_sum(sq, sred);
  if (t == 0) cap_rn[b] = 1.0f / (sqrtf(tot) + 1e-8f);
}

// ---- img path: leaky-relu + l2norm over R, keep per-(b,d) sums ----
__global__ __launch_bounds__(256) void img_kernel(const float* __restrict__ img,
    float* __restrict__ rowsum, float* __restrict__ rowss) {
  int b = blockIdx.x, t = threadIdx.x;
  const float4* src = reinterpret_cast<const float4*>(img) + (size_t)b * (R_ * D_ / 4);
  float s1[4] = {0, 0, 0, 0}, s2[4] = {0, 0, 0, 0};
  for (int r = 0; r < R_; ++r) {
    float4 v = src[r * (D_ / 4) + t];
    float y0 = lrelu(v.x), y1 = lrelu(v.y), y2 = lrelu(v.z), y3 = lrelu(v.w);
    s1[0] += y0; s1[1] += y1; s1[2] += y2; s1[3] += y3;
    s2[0] += y0 * y0; s2[1] += y1 * y1; s2[2] += y2 * y2; s2[3] += y3 * y3;
  }
  float4 rs, ss;
  {
    float n0 = sqrtf(s2[0]) + 1e-8f, n1 = sqrtf(s2[1]) + 1e-8f;
    float n2 = sqrtf(s2[2]) + 1e-8f, n3 = sqrtf(s2[3]) + 1e-8f;
    rs.x = s1[0] / n0; rs.y = s1[1] / n1; rs.z = s1[2] / n2; rs.w = s1[3] / n3;
    ss.x = s2[0] / (n0 * n0); ss.y = s2[1] / (n1 * n1);
    ss.z = s2[2] / (n2 * n2); ss.w = s2[3] / (n3 * n3);
  }
  reinterpret_cast<float4*>(rowsum)[b * (D_ / 4) + t] = rs;
  reinterpret_cast<float4*>(rowss)[b * (D_ / 4) + t] = ss;
}

// ---- BN batch stats: column reduction over b ----
__global__ __launch_bounds__(256) void stats_kernel(const float* __restrict__ rowsum,
    const float* __restrict__ rowss, const float* __restrict__ bn_w,
    float* __restrict__ mu, float* __restrict__ g) {
  int d = blockIdx.x * 256 + threadIdx.x;
  float cs = 0.0f, c2 = 0.0f;
  for (int b = 0; b < B_; ++b) {
    cs += rowsum[b * D_ + d];
    c2 += rowss[b * D_ + d];
  }
  const float inv = 1.0f / (float)(B_ * R_);
  float m = cs * inv, ex2 = c2 * inv;
  float var = ex2 - m * m;
  mu[d] = m;
  g[d] = bn_w[d] / sqrtf(var + 1e-5f);
}

// ---- base[b,d] = (rowsum/R - mu)*g + bn_b ----
__global__ __launch_bounds__(256) void base_kernel(const float* __restrict__ rowsum,
    const float* __restrict__ mu, const float* __restrict__ g,
    const float* __restrict__ bn_b, float* __restrict__ basep) {
  int i = blockIdx.x * 256 + threadIdx.x;  // float4 index over B*D/4
  int dq = i & (D_ / 4 - 1);
  float4 rs = reinterpret_cast<const float4*>(rowsum)[i];
  float4 m = reinterpret_cast<const float4*>(mu)[dq];
  float4 gg = reinterpret_cast<const float4*>(g)[dq];
  float4 bb = reinterpret_cast<const float4*>(bn_b)[dq];
  const float invR = 1.0f / (float)R_;
  float4 o;
  o.x = (rs.x * invR - m.x) * gg.x + bb.x;
  o.y = (rs.y * invR - m.y) * gg.y + bb.y;
  o.z = (rs.z * invR - m.z) * gg.z + bb.z;
  o.w = (rs.w * invR - m.w) * gg.w + bb.w;
  reinterpret_cast<float4*>(basep)[i] = o;
}

// ---- params = cap_mean @ fc_w^T + fc_b  (M=256,N=2048,K=1024) ----
// BM=32 (c), BN=64 (n), BK=32; grid (32 n-tiles, 8 c-tiles), 256 threads, 2x4/thread
__global__ __launch_bounds__(256) void params_gemm_kernel(
    const float* __restrict__ cap_mean, const float* __restrict__ fc_w,
    const float* __restrict__ fc_b, float* __restrict__ params) {
  __shared__ float As[32][36];  // [c][k], stride 36 keeps rows 16B-aligned
  __shared__ float Bs[32][64];  // [k][n]
  int t = threadIdx.x;
  int nt = blockIdx.x, ct = blockIdx.y;
  int tr = t >> 4, tc = t & 15;
  int ca = t >> 3, ka = (t & 7) << 2;
  int nb = t >> 2, kb = (t & 3) << 3;
  float acc[2][4] = {{0.0f, 0.0f, 0.0f, 0.0f}, {0.0f, 0.0f, 0.0f, 0.0f}};
  const float* arow = cap_mean + (size_t)(ct * 32 + ca) * D_;
  const float* brow = fc_w + (size_t)(nt * 64 + nb) * D_;
  for (int k0 = 0; k0 < D_; k0 += 32) {
    float4 av = *(const float4*)&arow[k0 + ka];
    *(float4*)&As[ca][ka] = av;
    float4 b0 = *(const float4*)&brow[k0 + kb];
    float4 b1 = *(const float4*)&brow[k0 + kb + 4];
    Bs[kb + 0][nb] = b0.x; Bs[kb + 1][nb] = b0.y; Bs[kb + 2][nb] = b0.z; Bs[kb + 3][nb] = b0.w;
    Bs[kb + 4][nb] = b1.x; Bs[kb + 5][nb] = b1.y; Bs[kb + 6][nb] = b1.z; Bs[kb + 7][nb] = b1.w;
    __syncthreads();
#pragma unroll
    for (int kk = 0; kk < 32; ++kk) {
      float a0 = As[tr * 2][kk], a1 = As[tr * 2 + 1][kk];
      float4 q = *(const float4*)&Bs[kk][tc * 4];
      acc[0][0] += a0 * q.x; acc[0][1] += a0 * q.y; acc[0][2] += a0 * q.z; acc[0][3] += a0 * q.w;
      acc[1][0] += a1 * q.x; acc[1][1] += a1 * q.y; acc[1][2] += a1 * q.z; acc[1][3] += a1 * q.w;
    }
    __syncthreads();
  }
  float4 fb = *(const float4*)&fc_b[nt * 64 + tc * 4];
#pragma unroll
  for (int i = 0; i < 2; ++i) {
    int c = ct * 32 + tr * 2 + i;
    float4 o;
    o.x = acc[i][0] + fb.x; o.y = acc[i][1] + fb.y;
    o.z = acc[i][2] + fb.z; o.w = acc[i][3] + fb.w;
    *(float4*)&params[(size_t)c * 2048 + nt * 64 + tc * 4] = o;
  }
}

// ---- per-c scalars: constC[c] = rn*sum(beta*cm), BBc[c] = sum(beta^2) ----
__global__ __launch_bounds__(256) void scal_kernel(const float* __restrict__ params,
    const float* __restrict__ cap_mean, const float* __restrict__ cap_rn,
    float* __restrict__ constC, float* __restrict__ BBc) {
  __shared__ float sred[4], sred2[4];
  int c = blockIdx.x, t = threadIdx.x;
  float4 p0 = *(const float4*)&params[(size_t)c * 2048 + t * 8];
  float4 p1 = *(const float4*)&params[(size_t)c * 2048 + t * 8 + 4];
  float4 cm = *(const float4*)&cap_mean[(size_t)c * 1024 + t * 4];
  float sBc = p0.y * cm.x + p0.w * cm.y + p1.y * cm.z + p1.w * cm.w;
  float sB2 = p0.y * p0.y + p0.w * p0.w + p1.y * p1.y + p1.w * p1.w;
  float a = block_sum(sBc, sred);
  float bsum = block_sum(sB2, sred2);
  if (t == 0) {
    constC[c] = a * cap_rn[c];
    BBc[c] = bsum;
  }
}

// ---- fused 3-GEMM for sims numerator/denominator, split-K=8 ----
// tile: 32 b-rows x 64 c-cols, K-chunk = 128 (2 sub-chunks of 64)
__global__ __launch_bounds__(256) void sims_kernel(const float* __restrict__ basep,
    const float* __restrict__ params, const float* __restrict__ cap_mean,
    const float* __restrict__ cap_rn, float* __restrict__ Npart, float* __restrict__ Qpart) {
  __shared__ float Tb[64][32];
  __shared__ float Tacv[64][64];
  __shared__ float Ta2[64][64];
  __shared__ float Tab[64][64];
  int t = threadIdx.x;
  int bt = blockIdx.x, ct = blockIdx.y, kz = blockIdx.z;
  int tr = t >> 4, tc = t & 15;
  int bb_ = t >> 3, kb_ = (t & 7) << 3;
  int cc_ = t >> 2, dc_ = (t & 3) << 4;
  float rn_c = cap_rn[ct * 64 + cc_];
  const float* prow = params + (size_t)(ct * 64 + cc_) * 2048;
  const float* cmrow = cap_mean + (size_t)(ct * 64 + cc_) * 1024;
  const float* brow = basep + (size_t)(bt * 32 + bb_) * 1024;
  float accN[2][4] = {{0.0f, 0.0f, 0.0f, 0.0f}, {0.0f, 0.0f, 0.0f, 0.0f}};
  float accQ[2][4] = {{0.0f, 0.0f, 0.0f, 0.0f}, {0.0f, 0.0f, 0.0f, 0.0f}};
  for (int kc = 0; kc < 2; ++kc) {
    int k0 = kz * 128 + kc * 64;
    __syncthreads();  // protect LDS from previous iteration's readers
    {
      float4 v0 = *(const float4*)&brow[k0 + kb_];
      float4 v1 = *(const float4*)&brow[k0 + kb_ + 4];
      Tb[kb_ + 0][bb_] = v0.x; Tb[kb_ + 1][bb_] = v0.y;
      Tb[kb_ + 2][bb_] = v0.z; Tb[kb_ + 3][bb_] = v0.w;
      Tb[kb_ + 4][bb_] = v1.x; Tb[kb_ + 5][bb_] = v1.y;
      Tb[kb_ + 6][bb_] = v1.z; Tb[kb_ + 7][bb_] = v1.w;
    }
#pragma unroll
    for (int j = 0; j < 16; j += 4) {
      int d = dc_ + j;
      float4 p0 = *(const float4*)&prow[2 * (k0 + d)];
      float4 p1 = *(const float4*)&prow[2 * (k0 + d) + 4];
      float4 cm = *(const float4*)&cmrow[k0 + d];
      Tacv[d + 0][cc_] = p0.x * cm.x * rn_c;
      Ta2[d + 0][cc_] = p0.x * p0.x;
      Tab[d + 0][cc_] = 2.0f * p0.x * p0.y;
      Tacv[d + 1][cc_] = p0.z * cm.y * rn_c;
      Ta2[d + 1][cc_] = p0.z * p0.z;
      Tab[d + 1][cc_] = 2.0f * p0.z * p0.w;
      Tacv[d + 2][cc_] = p1.x * cm.z * rn_c;
      Ta2[d + 2][cc_] = p1.x * p1.x;
      Tab[d + 2][cc_] = 2.0f * p1.x * p1.y;
      Tacv[d + 3][cc_] = p1.z * cm.w * rn_c;
      Ta2[d + 3][cc_] = p1.z * p1.z;
      Tab[d + 3][cc_] = 2.0f * p1.z * p1.w;
    }
    __syncthreads();
#pragma unroll 16
    for (int kk = 0; kk < 64; ++kk) {
      float2 bv = *(const float2*)&Tb[kk][tr * 2];
      float4 acv = *(const float4*)&Tacv[kk][tc * 4];
      float4 a2v = *(const float4*)&Ta2[kk][tc * 4];
      float4 abv = *(const float4*)&Tab[kk][tc * 4];
      float b0 = bv.x, b1 = bv.y;
      float q0 = b0 * b0, q1 = b1 * b1;
      accN[0][0] += b0 * acv.x; accN[0][1] += b0 * acv.y;
      accN[0][2] += b0 * acv.z; accN[0][3] += b0 * acv.w;
      accN[1][0] += b1 * acv.x; accN[1][1] += b1 * acv.y;
      accN[1][2] += b1 * acv.z; accN[1][3] += b1 * acv.w;
      accQ[0][0] += q0 * a2v.x; accQ[0][1] += q0 * a2v.y;
      accQ[0][2] += q0 * a2v.z; accQ[0][3] += q0 * a2v.w;
      accQ[1][0] += q1 * a2v.x; accQ[1][1] += q1 * a2v.y;
      accQ[1][2] += q1 * a2v.z; accQ[1][3] += q1 * a2v.w;
      accQ[0][0] += b0 * abv.x; accQ[0][1] += b0 * abv.y;
      accQ[0][2] += b0 * abv.z; accQ[0][3] += b0 * abv.w;
      accQ[1][0] += b1 * abv.x; accQ[1][1] += b1 * abv.y;
      accQ[1][2] += b1 * abv.z; accQ[1][3] += b1 * abv.w;
    }
  }
  int br = bt * 32 + tr * 2;
  int c = ct * 64 + tc * 4;
#pragma unroll
  for (int i = 0; i < 2; ++i) {
    size_t o = ((size_t)kz * 256 + br + i) * 256 + c;
    *(float4*)&Npart[o] = make_float4(accN[i][0], accN[i][1], accN[i][2], accN[i][3]);
    *(float4*)&Qpart[o] = make_float4(accQ[i][0], accQ[i][1], accQ[i][2], accQ[i][3]);
  }
}

// ---- combine split-K partials, add per-c constants, normalize ----
__global__ __launch_bounds__(256) void final_kernel(const float* __restrict__ Npart,
    const float* __restrict__ Qpart, const float* __restrict__ constC,
    const float* __restrict__ BBc, float* __restrict__ out) {
  int b = blockIdx.x, c = threadIdx.x;
  float N = constC[c], Q = BBc[c];
#pragma unroll
  for (int kz = 0; kz < 8; ++kz) {
    size_t o = ((size_t)kz * 256 + b) * 256 + c;
    N += Npart[o];
    Q += Qpart[o];
  }
  out[b * 256 + c] = N / (sqrtf(Q) + 1e-8f);
}

extern "C" void kernel_launch(void* const* d_in, const int* in_sizes, int n_in,
                              void* d_out, int out_size, void* d_ws, size_t ws_size,
                              hipStream_t stream) {
  const float* img = (const float*)d_in[0];
  const float* cap = (const float*)d_in[1];
  const int* lens = (const int*)d_in[2];
  const float* fc_w = (const float*)d_in[3];
  const float* fc_b = (const float*)d_in[4];
  const float* bn_w = (const float*)d_in[5];
  const float* bn_b = (const float*)d_in[6];
  float* out = (float*)d_out;
  float* ws = (float*)d_ws;

  float* cap_mean = ws;                //  262144
  float* cap_rn   = ws + 262144;       //     256
  float* rowsum   = ws + 262400;       //  262144
  float* rowss    = ws + 524544;       //  262144
  float* mu       = ws + 786688;       //    1024
  float* g        = ws + 787712;       //    1024
  float* basep    = ws + 788736;       //  262144
  float* params   = ws + 1050880;      //  524288
  float* constC   = ws + 1575168;      //     256
  float* BBc      = ws + 1575424;      //     256
  float* Npart    = ws + 1575680;      //  524288
  float* Qpart    = ws + 2099968;      //  524288  -> total ~10.5 MB

  cap_kernel<<<256, 256, 0, stream>>>(cap, lens, cap_mean, cap_rn);
  img_kernel<<<256, 256, 0, stream>>>(img, rowsum, rowss);
  stats_kernel<<<4, 256, 0, stream>>>(rowsum, rowss, bn_w, mu, g);
  base_kernel<<<256, 256, 0, stream>>>(rowsum, mu, g, bn_b, basep);
  params_gemm_kernel<<<dim3(32, 8), 256, 0, stream>>>(cap_mean, fc_w, fc_b, params);
  scal_kernel<<<256, 256, 0, stream>>>(params, cap_mean, cap_rn, constC, BBc);
  sims_kernel<<<dim3(8, 4, 8), 256, 0, stream>>>(basep, params, cap_mean, cap_rn, Npart, Qpart);
  final_kernel<<<256, 256, 0, stream>>>(Npart, Qpart, constC, BBc, out);
}

// Round 2
// 85.741 us; speedup vs baseline: 1.1641x; 1.1641x over previous
//
#include <hip/hip_runtime.h>
#include <hip/hip_bf16.h>

#define B_ 256
#define R_ 36
#define T_ 64
#define D_ 1024

// XOR swizzles: make transposing scalar LDS stores and b128 reads <=2-way
#define SWZ64(k, c) ((c) ^ ((((k) >> 4) & 3) << 4))  // 64-wide tiles
#define SWZ32(k, b) ((b) ^ ((((k) >> 3) & 3) << 3))  // 32-wide tiles

__device__ __forceinline__ float lrelu(float x) { return x >= 0.0f ? x : 0.1f * x; }

// block-wide sum over 256 threads (4 waves)
__device__ __forceinline__ float block_sum(float v, float* sred) {
#pragma unroll
  for (int off = 32; off > 0; off >>= 1) v += __shfl_down(v, off, 64);
  int w = threadIdx.x >> 6;
  if ((threadIdx.x & 63) == 0) sred[w] = v;
  __syncthreads();
  float r = sred[0] + sred[1] + sred[2] + sred[3];
  __syncthreads();
  return r;
}

// ---- cap path: leaky-relu + l2norm over T + masked mean ----
// grid (256 b, 2 half), 256 threads, 2 d-floats per thread
__global__ __launch_bounds__(256) void cap_kernel(const float* __restrict__ cap,
    const int* __restrict__ lens, float* __restrict__ cap_mean) {
  int b = blockIdx.x;
  int d0 = blockIdx.y * 512 + threadIdx.x * 2;
  int len = lens[b];
  const float* src = cap + (size_t)b * (T_ * D_) + d0;
  float s20 = 0.f, s21 = 0.f, sm0 = 0.f, sm1 = 0.f;
#pragma unroll 8
  for (int tt = 0; tt < T_; ++tt) {
    float2 v = *(const float2*)&src[(size_t)tt * D_];
    float y0 = lrelu(v.x), y1 = lrelu(v.y);
    s20 += y0 * y0; s21 += y1 * y1;
    bool in = tt < len;
    sm0 += in ? y0 : 0.0f;
    sm1 += in ? y1 : 0.0f;
  }
  float il = 1.0f / (float)len;
  float2 cm;
  cm.x = sm0 / (sqrtf(s20) + 1e-8f) * il;
  cm.y = sm1 / (sqrtf(s21) + 1e-8f) * il;
  *(float2*)&cap_mean[(size_t)b * D_ + d0] = cm;
}

// ---- img path: leaky-relu + l2norm over R, keep per-(b,d) sums ----
__global__ __launch_bounds__(256) void img_kernel(const float* __restrict__ img,
    float* __restrict__ rowsum, float* __restrict__ rowss) {
  int b = blockIdx.x;
  int d0 = blockIdx.y * 512 + threadIdx.x * 2;
  const float* src = img + (size_t)b * (R_ * D_) + d0;
  float s10 = 0.f, s11 = 0.f, s20 = 0.f, s21 = 0.f;
#pragma unroll 6
  for (int r = 0; r < R_; ++r) {
    float2 v = *(const float2*)&src[(size_t)r * D_];
    float y0 = lrelu(v.x), y1 = lrelu(v.y);
    s10 += y0; s11 += y1;
    s20 += y0 * y0; s21 += y1 * y1;
  }
  float n0 = sqrtf(s20) + 1e-8f, n1 = sqrtf(s21) + 1e-8f;
  float2 rs, ss;
  rs.x = s10 / n0; rs.y = s11 / n1;
  ss.x = s20 / (n0 * n0); ss.y = s21 / (n1 * n1);
  *(float2*)&rowsum[(size_t)b * D_ + d0] = rs;
  *(float2*)&rowss[(size_t)b * D_ + d0] = ss;
}

// ---- BN batch stats: column reduction over b; grid 16, block handles 64 d ----
__global__ __launch_bounds__(256) void stats_kernel(const float* __restrict__ rowsum,
    const float* __restrict__ rowss, const float* __restrict__ bn_w,
    float* __restrict__ mu, float* __restrict__ g) {
  __shared__ float s1[4][64], s2[4][64];
  int dl = threadIdx.x & 63;
  int d = blockIdx.x * 64 + dl;
  int bg = threadIdx.x >> 6;
  float cs = 0.0f, c2 = 0.0f;
  for (int b = bg * 64; b < bg * 64 + 64; ++b) {
    cs += rowsum[(size_t)b * D_ + d];
    c2 += rowss[(size_t)b * D_ + d];
  }
  s1[bg][dl] = cs;
  s2[bg][dl] = c2;
  __syncthreads();
  if (threadIdx.x < 64) {
    cs = s1[0][dl] + s1[1][dl] + s1[2][dl] + s1[3][dl];
    c2 = s2[0][dl] + s2[1][dl] + s2[2][dl] + s2[3][dl];
    const float inv = 1.0f / (float)(B_ * R_);
    float m = cs * inv, ex2 = c2 * inv;
    float var = ex2 - m * m;
    mu[d] = m;
    g[d] = bn_w[d] / sqrtf(var + 1e-5f);
  }
}

// ---- base[b,d] = (rowsum/R - mu)*g + bn_b ----
__global__ __launch_bounds__(256) void base_kernel(const float* __restrict__ rowsum,
    const float* __restrict__ mu, const float* __restrict__ g,
    const float* __restrict__ bn_b, float* __restrict__ basep) {
  int i = blockIdx.x * 256 + threadIdx.x;  // float4 index over B*D/4
  int dq = i & (D_ / 4 - 1);
  float4 rs = reinterpret_cast<const float4*>(rowsum)[i];
  float4 m = reinterpret_cast<const float4*>(mu)[dq];
  float4 gg = reinterpret_cast<const float4*>(g)[dq];
  float4 bb = reinterpret_cast<const float4*>(bn_b)[dq];
  const float invR = 1.0f / (float)R_;
  float4 o;
  o.x = (rs.x * invR - m.x) * gg.x + bb.x;
  o.y = (rs.y * invR - m.y) * gg.y + bb.y;
  o.z = (rs.z * invR - m.z) * gg.z + bb.z;
  o.w = (rs.w * invR - m.w) * gg.w + bb.w;
  reinterpret_cast<float4*>(basep)[i] = o;
}

// ---- params = cap_mean @ fc_w^T  (M=256,N=2048,K=1024), split-K=4 ----
// grid (nt=32, ct=4, kz=4), 256 threads; tile 64c x 64n, K-chunk 256, BK=32
// k-major swizzled LDS, 4x4 acc per thread
__global__ __launch_bounds__(256) void params_gemm_kernel(
    const float* __restrict__ cap_mean, const float* __restrict__ fc_w,
    float* __restrict__ Ppart) {
  __shared__ float As[32][64];  // [k][c], swizzled
  __shared__ float Bs[32][64];  // [k][n], swizzled
  int t = threadIdx.x;
  int nt = blockIdx.x, ct = blockIdx.y, kz = blockIdx.z;
  int tr = t >> 4, tc = t & 15;           // output: c-rows tr*4.., n-cols tc*4..
  int cs = t >> 2, k0 = (t & 3) << 3;     // staging: row cs, 8 k from k0
  const float* arow = cap_mean + (size_t)(ct * 64 + cs) * D_ + kz * 256;
  const float* brow = fc_w + (size_t)(nt * 64 + cs) * D_ + kz * 256;
  float acc[4][4] = {};
  int sa = SWZ64(k0, cs);  // (k0..k0+7)>>4 constant -> swizzled col constant
  for (int kb = 0; kb < 256; kb += 32) {
    float4 a0 = *(const float4*)&arow[kb + k0];
    float4 a1 = *(const float4*)&arow[kb + k0 + 4];
    float4 b0 = *(const float4*)&brow[kb + k0];
    float4 b1 = *(const float4*)&brow[kb + k0 + 4];
    __syncthreads();  // previous iter's readers done
    As[k0 + 0][sa] = a0.x; As[k0 + 1][sa] = a0.y; As[k0 + 2][sa] = a0.z; As[k0 + 3][sa] = a0.w;
    As[k0 + 4][sa] = a1.x; As[k0 + 5][sa] = a1.y; As[k0 + 6][sa] = a1.z; As[k0 + 7][sa] = a1.w;
    Bs[k0 + 0][sa] = b0.x; Bs[k0 + 1][sa] = b0.y; Bs[k0 + 2][sa] = b0.z; Bs[k0 + 3][sa] = b0.w;
    Bs[k0 + 4][sa] = b1.x; Bs[k0 + 5][sa] = b1.y; Bs[k0 + 6][sa] = b1.z; Bs[k0 + 7][sa] = b1.w;
    __syncthreads();
#pragma unroll
    for (int kk = 0; kk < 32; ++kk) {
      float4 av = *(const float4*)&As[kk][SWZ64(kk, tr * 4)];
      float4 bv = *(const float4*)&Bs[kk][SWZ64(kk, tc * 4)];
      acc[0][0] += av.x * bv.x; acc[0][1] += av.x * bv.y; acc[0][2] += av.x * bv.z; acc[0][3] += av.x * bv.w;
      acc[1][0] += av.y * bv.x; acc[1][1] += av.y * bv.y; acc[1][2] += av.y * bv.z; acc[1][3] += av.y * bv.w;
      acc[2][0] += av.z * bv.x; acc[2][1] += av.z * bv.y; acc[2][2] += av.z * bv.z; acc[2][3] += av.z * bv.w;
      acc[3][0] += av.w * bv.x; acc[3][1] += av.w * bv.y; acc[3][2] += av.w * bv.z; acc[3][3] += av.w * bv.w;
    }
  }
  int c = ct * 64 + tr * 4;
  int n = nt * 64 + tc * 4;
#pragma unroll
  for (int i = 0; i < 4; ++i) {
    *(float4*)&Ppart[((size_t)kz * 256 + c + i) * 2048 + n] =
        make_float4(acc[i][0], acc[i][1], acc[i][2], acc[i][3]);
  }
}

// ---- reduce split-K partials + fc_b -> params ----
__global__ __launch_bounds__(256) void reduce_params_kernel(const float* __restrict__ Ppart,
    const float* __restrict__ fc_b, float* __restrict__ params) {
  int i = blockIdx.x * 256 + threadIdx.x;  // float4 index, 131072 total
  int n4 = i & 511;
  float4 acc = reinterpret_cast<const float4*>(fc_b)[n4];
#pragma unroll
  for (int kz = 0; kz < 4; ++kz) {
    float4 p = reinterpret_cast<const float4*>(Ppart)[(size_t)kz * 131072 + i];
    acc.x += p.x; acc.y += p.y; acc.z += p.z; acc.w += p.w;
  }
  reinterpret_cast<float4*>(params)[i] = acc;
}

// ---- per-c scalars: cap_rn, constC = rn*sum(beta*cm), BBc = sum(beta^2) ----
__global__ __launch_bounds__(256) void scal_kernel(const float* __restrict__ params,
    const float* __restrict__ cap_mean, float* __restrict__ cap_rn,
    float* __restrict__ constC, float* __restrict__ BBc) {
  __shared__ float sred[4], sred2[4], sred3[4];
  int c = blockIdx.x, t = threadIdx.x;
  float4 p0 = *(const float4*)&params[(size_t)c * 2048 + t * 8];
  float4 p1 = *(const float4*)&params[(size_t)c * 2048 + t * 8 + 4];
  float4 cm = *(const float4*)&cap_mean[(size_t)c * 1024 + t * 4];
  float sBc = p0.y * cm.x + p0.w * cm.y + p1.y * cm.z + p1.w * cm.w;
  float sB2 = p0.y * p0.y + p0.w * p0.w + p1.y * p1.y + p1.w * p1.w;
  float scm = cm.x * cm.x + cm.y * cm.y + cm.z * cm.z + cm.w * cm.w;
  float a = block_sum(sBc, sred);
  float bsum = block_sum(sB2, sred2);
  float cq = block_sum(scm, sred3);
  if (t == 0) {
    float rn = 1.0f / (sqrtf(cq) + 1e-8f);
    cap_rn[c] = rn;
    constC[c] = a * rn;
    BBc[c] = bsum;
  }
}

// ---- fused 3-GEMM for sims numerator/denominator, split-K=16 ----
// grid (8 bt, 4 ct, 16 kz); tile 32b x 64c, K-chunk 64
__global__ __launch_bounds__(256) void sims_kernel(const float* __restrict__ basep,
    const float* __restrict__ params, const float* __restrict__ cap_mean,
    const float* __restrict__ cap_rn, float* __restrict__ Npart, float* __restrict__ Qpart) {
  __shared__ float Tb[64][32];
  __shared__ float Tacv[64][64];
  __shared__ float Ta2[64][64];
  __shared__ float Tab[64][64];
  int t = threadIdx.x;
  int bt = blockIdx.x, ct = blockIdx.y, kz = blockIdx.z;
  int k0 = kz * 64;
  int tr = t >> 4, tc = t & 15;
  int bb = t >> 3, kb = (t & 7) << 3;   // Tb staging
  int cc = t >> 2, dc = (t & 3) << 4;   // T* staging
  float rn_c = cap_rn[ct * 64 + cc];
  const float* prow = params + (size_t)(ct * 64 + cc) * 2048 + 2 * k0;
  const float* cmrow = cap_mean + (size_t)(ct * 64 + cc) * 1024 + k0;
  const float* brow = basep + (size_t)(bt * 32 + bb) * 1024 + k0;
  // stage Tb[k][b] (transposed, swizzled)
  {
    float4 v0 = *(const float4*)&brow[kb];
    float4 v1 = *(const float4*)&brow[kb + 4];
    int sb = SWZ32(kb, bb);  // (kb..kb+7)>>3 constant
    Tb[kb + 0][sb] = v0.x; Tb[kb + 1][sb] = v0.y; Tb[kb + 2][sb] = v0.z; Tb[kb + 3][sb] = v0.w;
    Tb[kb + 4][sb] = v1.x; Tb[kb + 5][sb] = v1.y; Tb[kb + 6][sb] = v1.z; Tb[kb + 7][sb] = v1.w;
  }
  // stage Tacv/Ta2/Tab [d][c] (swizzled)
  int sc = SWZ64(dc, cc);  // (dc..dc+15)>>4 constant
#pragma unroll
  for (int j = 0; j < 16; j += 4) {
    int d = dc + j;
    float4 p0 = *(const float4*)&prow[2 * d];
    float4 p1 = *(const float4*)&prow[2 * d + 4];
    float4 cm = *(const float4*)&cmrow[d];
    Tacv[d + 0][sc] = p0.x * cm.x * rn_c; Ta2[d + 0][sc] = p0.x * p0.x; Tab[d + 0][sc] = 2.f * p0.x * p0.y;
    Tacv[d + 1][sc] = p0.z * cm.y * rn_c; Ta2[d + 1][sc] = p0.z * p0.z; Tab[d + 1][sc] = 2.f * p0.z * p0.w;
    Tacv[d + 2][sc] = p1.x * cm.z * rn_c; Ta2[d + 2][sc] = p1.x * p1.x; Tab[d + 2][sc] = 2.f * p1.x * p1.y;
    Tacv[d + 3][sc] = p1.z * cm.w * rn_c; Ta2[d + 3][sc] = p1.z * p1.z; Tab[d + 3][sc] = 2.f * p1.z * p1.w;
  }
  __syncthreads();
  float accN[2][4] = {};
  float accQ[2][4] = {};
#pragma unroll 8
  for (int kk = 0; kk < 64; ++kk) {
    float2 bv = *(const float2*)&Tb[kk][SWZ32(kk, tr * 2)];
    float4 acv = *(const float4*)&Tacv[kk][SWZ64(kk, tc * 4)];
    float4 a2v = *(const float4*)&Ta2[kk][SWZ64(kk, tc * 4)];
    float4 abv = *(const float4*)&Tab[kk][SWZ64(kk, tc * 4)];
    float b0 = bv.x, b1 = bv.y;
    float q0 = b0 * b0, q1 = b1 * b1;
    accN[0][0] += b0 * acv.x; accN[0][1] += b0 * acv.y; accN[0][2] += b0 * acv.z; accN[0][3] += b0 * acv.w;
    accN[1][0] += b1 * acv.x; accN[1][1] += b1 * acv.y; accN[1][2] += b1 * acv.z; accN[1][3] += b1 * acv.w;
    accQ[0][0] += q0 * a2v.x; accQ[0][1] += q0 * a2v.y; accQ[0][2] += q0 * a2v.z; accQ[0][3] += q0 * a2v.w;
    accQ[1][0] += q1 * a2v.x; accQ[1][1] += q1 * a2v.y; accQ[1][2] += q1 * a2v.z; accQ[1][3] += q1 * a2v.w;
    accQ[0][0] += b0 * abv.x; accQ[0][1] += b0 * abv.y; accQ[0][2] += b0 * abv.z; accQ[0][3] += b0 * abv.w;
    accQ[1][0] += b1 * abv.x; accQ[1][1] += b1 * abv.y; accQ[1][2] += b1 * abv.z; accQ[1][3] += b1 * abv.w;
  }
  int br = bt * 32 + tr * 2;
  int c = ct * 64 + tc * 4;
#pragma unroll
  for (int i = 0; i < 2; ++i) {
    size_t o = ((size_t)kz * 256 + br + i) * 256 + c;
    *(float4*)&Npart[o] = make_float4(accN[i][0], accN[i][1], accN[i][2], accN[i][3]);
    *(float4*)&Qpart[o] = make_float4(accQ[i][0], accQ[i][1], accQ[i][2], accQ[i][3]);
  }
}

// ---- combine split-K partials, add per-c constants, normalize ----
__global__ __launch_bounds__(256) void final_kernel(const float* __restrict__ Npart,
    const float* __restrict__ Qpart, const float* __restrict__ constC,
    const float* __restrict__ BBc, float* __restrict__ out) {
  int b = blockIdx.x, c = threadIdx.x;
  float N = constC[c], Q = BBc[c];
#pragma unroll
  for (int kz = 0; kz < 16; ++kz) {
    size_t o = ((size_t)kz * 256 + b) * 256 + c;
    N += Npart[o];
    Q += Qpart[o];
  }
  out[b * 256 + c] = N / (sqrtf(Q) + 1e-8f);
}

extern "C" void kernel_launch(void* const* d_in, const int* in_sizes, int n_in,
                              void* d_out, int out_size, void* d_ws, size_t ws_size,
                              hipStream_t stream) {
  const float* img = (const float*)d_in[0];
  const float* cap = (const float*)d_in[1];
  const int* lens = (const int*)d_in[2];
  const float* fc_w = (const float*)d_in[3];
  const float* fc_b = (const float*)d_in[4];
  const float* bn_w = (const float*)d_in[5];
  const float* bn_b = (const float*)d_in[6];
  float* out = (float*)d_out;
  float* ws = (float*)d_ws;

  float* cap_mean = ws;                //  262144
  float* cap_rn   = ws + 262144;       //     256
  float* rowsum   = ws + 262400;       //  262144
  float* rowss    = ws + 524544;       //  262144
  float* mu       = ws + 786688;       //    1024
  float* g        = ws + 787712;       //    1024
  float* basep    = ws + 788736;       //  262144
  float* params   = ws + 1050880;      //  524288
  float* constC   = ws + 1575168;      //     256
  float* BBc      = ws + 1575424;      //     256
  float* region   = ws + 1575680;      // 2097152 shared: Ppart then Npart/Qpart
  float* Ppart    = region;            // 4 * 524288
  float* Npart    = region;            // 16 * 65536
  float* Qpart    = region + 1048576;  // 16 * 65536   total ws ~14.7 MB

  cap_kernel<<<dim3(256, 2), 256, 0, stream>>>(cap, lens, cap_mean);
  img_kernel<<<dim3(256, 2), 256, 0, stream>>>(img, rowsum, rowss);
  stats_kernel<<<16, 256, 0, stream>>>(rowsum, rowss, bn_w, mu, g);
  base_kernel<<<256, 256, 0, stream>>>(rowsum, mu, g, bn_b, basep);
  params_gemm_kernel<<<dim3(32, 4, 4), 256, 0, stream>>>(cap_mean, fc_w, Ppart);
  reduce_params_kernel<<<512, 256, 0, stream>>>(Ppart, fc_b, params);
  scal_kernel<<<256, 256, 0, stream>>>(params, cap_mean, cap_rn, constC, BBc);
  sims_kernel<<<dim3(8, 4, 16), 256, 0, stream>>>(basep, params, cap_mean, cap_rn, Npart, Qpart);
  final_kernel<<<256, 256, 0, stream>>>(Npart, Qpart, constC, BBc, out);
}

// Round 3
// 64.691 us; speedup vs baseline: 1.5429x; 1.3254x over previous
//
#include <hip/hip_runtime.h>
#include <hip/hip_bf16.h>

#define B_ 256
#define R_ 36
#define T_ 64
#define D_ 1024

// XOR swizzles: make transposing scalar LDS stores and b128 reads <=2-way
#define SWZ64(k, c) ((c) ^ ((((k) >> 4) & 3) << 4))  // 64-wide tiles
#define SWZ32(k, b) ((b) ^ ((((k) >> 3) & 3) << 3))  // 32-wide tiles

__device__ __forceinline__ float lrelu(float x) { return x >= 0.0f ? x : 0.1f * x; }

// block-wide sum over 256 threads (4 waves)
__device__ __forceinline__ float block_sum(float v, float* sred) {
#pragma unroll
  for (int off = 32; off > 0; off >>= 1) v += __shfl_down(v, off, 64);
  int w = threadIdx.x >> 6;
  if ((threadIdx.x & 63) == 0) sred[w] = v;
  __syncthreads();
  float r = sred[0] + sred[1] + sred[2] + sred[3];
  __syncthreads();
  return r;
}

// ---- fused input streaming: cap path (blocks 0..511) + img path (512..1023) ----
__global__ __launch_bounds__(256) void input_kernel(const float* __restrict__ cap,
    const float* __restrict__ img, const int* __restrict__ lens,
    float* __restrict__ cap_mean, float* __restrict__ rowsum, float* __restrict__ rowss) {
  int bid = blockIdx.x;
  if (bid < 512) {
    int b = bid >> 1;
    int d0 = (bid & 1) * 512 + threadIdx.x * 2;
    int len = lens[b];
    const float* src = cap + (size_t)b * (T_ * D_) + d0;
    float s20 = 0.f, s21 = 0.f, sm0 = 0.f, sm1 = 0.f;
#pragma unroll 8
    for (int tt = 0; tt < T_; ++tt) {
      float2 v = *(const float2*)&src[(size_t)tt * D_];
      float y0 = lrelu(v.x), y1 = lrelu(v.y);
      s20 += y0 * y0; s21 += y1 * y1;
      bool in = tt < len;
      sm0 += in ? y0 : 0.0f;
      sm1 += in ? y1 : 0.0f;
    }
    float il = 1.0f / (float)len;
    float2 cm;
    cm.x = sm0 / (sqrtf(s20) + 1e-8f) * il;
    cm.y = sm1 / (sqrtf(s21) + 1e-8f) * il;
    *(float2*)&cap_mean[(size_t)b * D_ + d0] = cm;
  } else {
    int b = (bid - 512) >> 1;
    int d0 = ((bid - 512) & 1) * 512 + threadIdx.x * 2;
    const float* src = img + (size_t)b * (R_ * D_) + d0;
    float s10 = 0.f, s11 = 0.f, s20 = 0.f, s21 = 0.f;
#pragma unroll 6
    for (int r = 0; r < R_; ++r) {
      float2 v = *(const float2*)&src[(size_t)r * D_];
      float y0 = lrelu(v.x), y1 = lrelu(v.y);
      s10 += y0; s11 += y1;
      s20 += y0 * y0; s21 += y1 * y1;
    }
    float n0 = sqrtf(s20) + 1e-8f, n1 = sqrtf(s21) + 1e-8f;
    float2 rs, ss;
    rs.x = s10 / n0; rs.y = s11 / n1;
    ss.x = s20 / (n0 * n0); ss.y = s21 / (n1 * n1);
    *(float2*)&rowsum[(size_t)b * D_ + d0] = rs;
    *(float2*)&rowss[(size_t)b * D_ + d0] = ss;
  }
}

// ---- fused: params GEMM (blocks 0..511) + BN stats (blocks 512..527) ----
// GEMM: params = cap_mean @ fc_w^T (M=256,N=2048,K=1024), split-K=4,
//   tile 64c x 64n, K-chunk 256, BK=32, k-major swizzled LDS, 4x4 acc/thread
// stats: g[d] = bn_w/sqrt(var+eps), h[d] = mu*g - bn_b
__global__ __launch_bounds__(256) void gemm_stats_kernel(
    const float* __restrict__ cap_mean, const float* __restrict__ fc_w,
    const float* __restrict__ rowsum, const float* __restrict__ rowss,
    const float* __restrict__ bn_w, const float* __restrict__ bn_b,
    float* __restrict__ Ppart, float* __restrict__ g, float* __restrict__ h) {
  __shared__ float As[32][64];  // [k][c], swizzled
  __shared__ float Bs[32][64];  // [k][n], swizzled
  __shared__ float s1[4][64], s2[4][64];
  int bid = blockIdx.x;
  int t = threadIdx.x;
  if (bid < 512) {
    int nt = bid & 31, ct = (bid >> 5) & 3, kz = bid >> 7;
    int tr = t >> 4, tc = t & 15;           // output: c-rows tr*4.., n-cols tc*4..
    int cs = t >> 2, k0 = (t & 3) << 3;     // staging: row cs, 8 k from k0
    const float* arow = cap_mean + (size_t)(ct * 64 + cs) * D_ + kz * 256;
    const float* brow = fc_w + (size_t)(nt * 64 + cs) * D_ + kz * 256;
    float acc[4][4] = {};
    int sa = SWZ64(k0, cs);
    for (int kb = 0; kb < 256; kb += 32) {
      float4 a0 = *(const float4*)&arow[kb + k0];
      float4 a1 = *(const float4*)&arow[kb + k0 + 4];
      float4 b0 = *(const float4*)&brow[kb + k0];
      float4 b1 = *(const float4*)&brow[kb + k0 + 4];
      __syncthreads();  // previous iter's readers done
      As[k0 + 0][sa] = a0.x; As[k0 + 1][sa] = a0.y; As[k0 + 2][sa] = a0.z; As[k0 + 3][sa] = a0.w;
      As[k0 + 4][sa] = a1.x; As[k0 + 5][sa] = a1.y; As[k0 + 6][sa] = a1.z; As[k0 + 7][sa] = a1.w;
      Bs[k0 + 0][sa] = b0.x; Bs[k0 + 1][sa] = b0.y; Bs[k0 + 2][sa] = b0.z; Bs[k0 + 3][sa] = b0.w;
      Bs[k0 + 4][sa] = b1.x; Bs[k0 + 5][sa] = b1.y; Bs[k0 + 6][sa] = b1.z; Bs[k0 + 7][sa] = b1.w;
      __syncthreads();
#pragma unroll
      for (int kk = 0; kk < 32; ++kk) {
        float4 av = *(const float4*)&As[kk][SWZ64(kk, tr * 4)];
        float4 bv = *(const float4*)&Bs[kk][SWZ64(kk, tc * 4)];
        acc[0][0] += av.x * bv.x; acc[0][1] += av.x * bv.y; acc[0][2] += av.x * bv.z; acc[0][3] += av.x * bv.w;
        acc[1][0] += av.y * bv.x; acc[1][1] += av.y * bv.y; acc[1][2] += av.y * bv.z; acc[1][3] += av.y * bv.w;
        acc[2][0] += av.z * bv.x; acc[2][1] += av.z * bv.y; acc[2][2] += av.z * bv.z; acc[2][3] += av.z * bv.w;
        acc[3][0] += av.w * bv.x; acc[3][1] += av.w * bv.y; acc[3][2] += av.w * bv.z; acc[3][3] += av.w * bv.w;
      }
    }
    int c = ct * 64 + tr * 4;
    int n = nt * 64 + tc * 4;
#pragma unroll
    for (int i = 0; i < 4; ++i) {
      *(float4*)&Ppart[((size_t)kz * 256 + c + i) * 2048 + n] =
          make_float4(acc[i][0], acc[i][1], acc[i][2], acc[i][3]);
    }
  } else {
    int sb = bid - 512;
    int dl = t & 63;
    int d = sb * 64 + dl;
    int bg = t >> 6;
    float cs = 0.0f, c2 = 0.0f;
    for (int b = bg * 64; b < bg * 64 + 64; ++b) {
      cs += rowsum[(size_t)b * D_ + d];
      c2 += rowss[(size_t)b * D_ + d];
    }
    s1[bg][dl] = cs;
    s2[bg][dl] = c2;
    __syncthreads();
    if (t < 64) {
      cs = s1[0][dl] + s1[1][dl] + s1[2][dl] + s1[3][dl];
      c2 = s2[0][dl] + s2[1][dl] + s2[2][dl] + s2[3][dl];
      const float inv = 1.0f / (float)(B_ * R_);
      float m = cs * inv, ex2 = c2 * inv;
      float var = ex2 - m * m;
      float gg = bn_w[d] / sqrtf(var + 1e-5f);
      g[d] = gg;
      h[d] = m * gg - bn_b[d];
    }
  }
}

// ---- fused: reduce split-K partials + fc_b -> params; per-c scalars ----
// grid 256 (one c per block); thread t owns n-cols [8t, 8t+8)
__global__ __launch_bounds__(256) void reduce_scal_kernel(const float* __restrict__ Ppart,
    const float* __restrict__ fc_b, const float* __restrict__ cap_mean,
    float* __restrict__ params, float* __restrict__ rawC, float* __restrict__ BBc,
    float* __restrict__ rn) {
  __shared__ float sred[4], sred2[4], sred3[4];
  int c = blockIdx.x, t = threadIdx.x;
  float4 p0 = reinterpret_cast<const float4*>(fc_b)[2 * t];
  float4 p1 = reinterpret_cast<const float4*>(fc_b)[2 * t + 1];
#pragma unroll
  for (int kz = 0; kz < 4; ++kz) {
    size_t base4 = ((size_t)kz * 256 + c) * 512;
    float4 q0 = reinterpret_cast<const float4*>(Ppart)[base4 + 2 * t];
    float4 q1 = reinterpret_cast<const float4*>(Ppart)[base4 + 2 * t + 1];
    p0.x += q0.x; p0.y += q0.y; p0.z += q0.z; p0.w += q0.w;
    p1.x += q1.x; p1.y += q1.y; p1.z += q1.z; p1.w += q1.w;
  }
  reinterpret_cast<float4*>(params)[(size_t)c * 512 + 2 * t] = p0;
  reinterpret_cast<float4*>(params)[(size_t)c * 512 + 2 * t + 1] = p1;
  float4 cm = reinterpret_cast<const float4*>(cap_mean)[(size_t)c * 256 + t];
  float sBc = p0.y * cm.x + p0.w * cm.y + p1.y * cm.z + p1.w * cm.w;
  float sB2 = p0.y * p0.y + p0.w * p0.w + p1.y * p1.y + p1.w * p1.w;
  float scm = cm.x * cm.x + cm.y * cm.y + cm.z * cm.z + cm.w * cm.w;
  float a = block_sum(sBc, sred);
  float bsum = block_sum(sB2, sred2);
  float cq = block_sum(scm, sred3);
  if (t == 0) {
    rawC[c] = a;
    BBc[c] = bsum;
    rn[c] = 1.0f / (sqrtf(cq) + 1e-8f);
  }
}

// ---- fused 3-GEMM for sims numerator/denominator, split-K=16 ----
// grid (8 bt, 4 ct, 16 kz); tile 32b x 64c, K-chunk 64; base computed on the fly
__global__ __launch_bounds__(256) void sims_kernel(const float* __restrict__ rowsum,
    const float* __restrict__ g, const float* __restrict__ h,
    const float* __restrict__ params, const float* __restrict__ cap_mean,
    float* __restrict__ Npart, float* __restrict__ Qpart) {
  __shared__ float Tb[64][32];
  __shared__ float Tacv[64][64];
  __shared__ float Ta2[64][64];
  __shared__ float Tab[64][64];
  int t = threadIdx.x;
  int bt = blockIdx.x, ct = blockIdx.y, kz = blockIdx.z;
  int k0 = kz * 64;
  int tr = t >> 4, tc = t & 15;
  int bb = t >> 3, kb = (t & 7) << 3;   // Tb staging
  int cc = t >> 2, dc = (t & 3) << 4;   // T* staging
  const float* prow = params + (size_t)(ct * 64 + cc) * 2048 + 2 * k0;
  const float* cmrow = cap_mean + (size_t)(ct * 64 + cc) * 1024 + k0;
  const float* rsrow = rowsum + (size_t)(bt * 32 + bb) * 1024 + k0;
  const float invR = 1.0f / (float)R_;
  // stage Tb[k][b] = base (transposed, swizzled): base = rs*invR*g - h
  {
    float4 v0 = *(const float4*)&rsrow[kb];
    float4 v1 = *(const float4*)&rsrow[kb + 4];
    float4 g0 = *(const float4*)&g[k0 + kb];
    float4 g1 = *(const float4*)&g[k0 + kb + 4];
    float4 h0 = *(const float4*)&h[k0 + kb];
    float4 h1 = *(const float4*)&h[k0 + kb + 4];
    int sb = SWZ32(kb, bb);
    Tb[kb + 0][sb] = v0.x * invR * g0.x - h0.x;
    Tb[kb + 1][sb] = v0.y * invR * g0.y - h0.y;
    Tb[kb + 2][sb] = v0.z * invR * g0.z - h0.z;
    Tb[kb + 3][sb] = v0.w * invR * g0.w - h0.w;
    Tb[kb + 4][sb] = v1.x * invR * g1.x - h1.x;
    Tb[kb + 5][sb] = v1.y * invR * g1.y - h1.y;
    Tb[kb + 6][sb] = v1.z * invR * g1.z - h1.z;
    Tb[kb + 7][sb] = v1.w * invR * g1.w - h1.w;
  }
  // stage Tacv/Ta2/Tab [d][c] (swizzled); rn folded into final kernel
  int sc = SWZ64(dc, cc);
#pragma unroll
  for (int j = 0; j < 16; j += 4) {
    int d = dc + j;
    float4 p0 = *(const float4*)&prow[2 * d];
    float4 p1 = *(const float4*)&prow[2 * d + 4];
    float4 cm = *(const float4*)&cmrow[d];
    Tacv[d + 0][sc] = p0.x * cm.x; Ta2[d + 0][sc] = p0.x * p0.x; Tab[d + 0][sc] = 2.f * p0.x * p0.y;
    Tacv[d + 1][sc] = p0.z * cm.y; Ta2[d + 1][sc] = p0.z * p0.z; Tab[d + 1][sc] = 2.f * p0.z * p0.w;
    Tacv[d + 2][sc] = p1.x * cm.z; Ta2[d + 2][sc] = p1.x * p1.x; Tab[d + 2][sc] = 2.f * p1.x * p1.y;
    Tacv[d + 3][sc] = p1.z * cm.w; Ta2[d + 3][sc] = p1.z * p1.z; Tab[d + 3][sc] = 2.f * p1.z * p1.w;
  }
  __syncthreads();
  float accN[2][4] = {};
  float accQ[2][4] = {};
#pragma unroll 8
  for (int kk = 0; kk < 64; ++kk) {
    float2 bv = *(const float2*)&Tb[kk][SWZ32(kk, tr * 2)];
    float4 acv = *(const float4*)&Tacv[kk][SWZ64(kk, tc * 4)];
    float4 a2v = *(const float4*)&Ta2[kk][SWZ64(kk, tc * 4)];
    float4 abv = *(const float4*)&Tab[kk][SWZ64(kk, tc * 4)];
    float b0 = bv.x, b1 = bv.y;
    float q0 = b0 * b0, q1 = b1 * b1;
    accN[0][0] += b0 * acv.x; accN[0][1] += b0 * acv.y; accN[0][2] += b0 * acv.z; accN[0][3] += b0 * acv.w;
    accN[1][0] += b1 * acv.x; accN[1][1] += b1 * acv.y; accN[1][2] += b1 * acv.z; accN[1][3] += b1 * acv.w;
    accQ[0][0] += q0 * a2v.x; accQ[0][1] += q0 * a2v.y; accQ[0][2] += q0 * a2v.z; accQ[0][3] += q0 * a2v.w;
    accQ[1][0] += q1 * a2v.x; accQ[1][1] += q1 * a2v.y; accQ[1][2] += q1 * a2v.z; accQ[1][3] += q1 * a2v.w;
    accQ[0][0] += b0 * abv.x; accQ[0][1] += b0 * abv.y; accQ[0][2] += b0 * abv.z; accQ[0][3] += b0 * abv.w;
    accQ[1][0] += b1 * abv.x; accQ[1][1] += b1 * abv.y; accQ[1][2] += b1 * abv.z; accQ[1][3] += b1 * abv.w;
  }
  int br = bt * 32 + tr * 2;
  int c = ct * 64 + tc * 4;
#pragma unroll
  for (int i = 0; i < 2; ++i) {
    size_t o = ((size_t)kz * 256 + br + i) * 256 + c;
    *(float4*)&Npart[o] = make_float4(accN[i][0], accN[i][1], accN[i][2], accN[i][3]);
    *(float4*)&Qpart[o] = make_float4(accQ[i][0], accQ[i][1], accQ[i][2], accQ[i][3]);
  }
}

// ---- combine split-K partials, apply per-c constants + rn, normalize ----
__global__ __launch_bounds__(256) void final_kernel(const float* __restrict__ Npart,
    const float* __restrict__ Qpart, const float* __restrict__ rawC,
    const float* __restrict__ BBc, const float* __restrict__ rn, float* __restrict__ out) {
  int b = blockIdx.x, c = threadIdx.x;
  float N = rawC[c], Q = BBc[c];
#pragma unroll
  for (int kz = 0; kz < 16; ++kz) {
    size_t o = ((size_t)kz * 256 + b) * 256 + c;
    N += Npart[o];
    Q += Qpart[o];
  }
  out[b * 256 + c] = N * rn[c] / (sqrtf(Q) + 1e-8f);
}

extern "C" void kernel_launch(void* const* d_in, const int* in_sizes, int n_in,
                              void* d_out, int out_size, void* d_ws, size_t ws_size,
                              hipStream_t stream) {
  const float* img = (const float*)d_in[0];
  const float* cap = (const float*)d_in[1];
  const int* lens = (const int*)d_in[2];
  const float* fc_w = (const float*)d_in[3];
  const float* fc_b = (const float*)d_in[4];
  const float* bn_w = (const float*)d_in[5];
  const float* bn_b = (const float*)d_in[6];
  float* out = (float*)d_out;
  float* ws = (float*)d_ws;

  float* cap_mean = ws;                //  262144
  float* rowsum   = ws + 262144;       //  262144
  float* rowss    = ws + 524288;       //  262144
  float* g        = ws + 786432;       //    1024
  float* h        = ws + 787456;       //    1024
  float* params   = ws + 788480;       //  524288
  float* rawC     = ws + 1312768;      //     256
  float* BBc      = ws + 1313024;      //     256
  float* rn       = ws + 1313280;      //     256
  float* region   = ws + 1313536;      // 2097152 shared: Ppart then Npart/Qpart
  float* Ppart    = region;            // 4 * 524288
  float* Npart    = region;            // 16 * 65536
  float* Qpart    = region + 1048576;  // 16 * 65536   total ws ~13.6 MB

  input_kernel<<<1024, 256, 0, stream>>>(cap, img, lens, cap_mean, rowsum, rowss);
  gemm_stats_kernel<<<528, 256, 0, stream>>>(cap_mean, fc_w, rowsum, rowss,
                                             bn_w, bn_b, Ppart, g, h);
  reduce_scal_kernel<<<256, 256, 0, stream>>>(Ppart, fc_b, cap_mean, params,
                                              rawC, BBc, rn);
  sims_kernel<<<dim3(8, 4, 16), 256, 0, stream>>>(rowsum, g, h, params, cap_mean,
                                                  Npart, Qpart);
  final_kernel<<<256, 256, 0, stream>>>(Npart, Qpart, rawC, BBc, rn, out);
}